// Round 1
// baseline (1228.305 us; speedup 1.0000x reference)
//
#include <hip/hip_runtime.h>
#include <hip/hip_bf16.h>
#include <cmath>

// Problem constants
#define BATCH   8
#define SEQ     1024
#define ROWS    8192        // BATCH*SEQ
#define DIM     768
#define VOCAB   50257
#define VPAD    50304       // VOCAB padded up to multiple of 128
#define NVB     393         // ceil(VOCAB/128) vocab tiles
#define NMB     64          // ROWS/128 row tiles

typedef __attribute__((ext_vector_type(8))) short bf16x8;
typedef __attribute__((ext_vector_type(4))) float f32x4;

__device__ __forceinline__ float b2f(ushort u) {
    return __uint_as_float(((unsigned int)u) << 16);
}

__device__ __forceinline__ ushort f2b(float f) {
    unsigned int u = __float_as_uint(f);
    u += 0x7FFFu + ((u >> 16) & 1u);   // round-to-nearest-even
    return (ushort)(u >> 16);
}

__device__ __forceinline__ float gelu_tanh(float x) {
    const float c = 0.7978845608028654f;   // sqrt(2/pi)
    float t = c * (x + 0.044715f * x * x * x);
    return 0.5f * x * (1.0f + tanhf(t));
}

__device__ __forceinline__ void async16(const void* g, void* l) {
    __builtin_amdgcn_global_load_lds((const __attribute__((address_space(1))) void*)g,
                                     (__attribute__((address_space(3))) void*)l,
                                     16, 0, 0);
}

// ---------------------------------------------------------------------------
// Kernel 1: W f32 -> bf16, zero-padded to VPAD rows
// ---------------------------------------------------------------------------
__global__ void convert_w(const float* __restrict__ W, ushort* __restrict__ Wb) {
    const size_t NQ  = (size_t)VPAD  * DIM / 4;   // padded quads
    const size_t NVQ = (size_t)VOCAB * DIM / 4;   // valid quads (VOCAB*DIM % 4 == 0)
    for (size_t q = (size_t)blockIdx.x * blockDim.x + threadIdx.x; q < NQ;
         q += (size_t)gridDim.x * blockDim.x) {
        ushort4 o;
        if (q < NVQ) {
            float4 f = ((const float4*)W)[q];
            o.x = f2b(f.x); o.y = f2b(f.y); o.z = f2b(f.z); o.w = f2b(f.w);
        } else {
            o.x = 0; o.y = 0; o.z = 0; o.w = 0;
        }
        ((ushort4*)Wb)[q] = o;
    }
}

// ---------------------------------------------------------------------------
// Kernel 2: x = gelu_tanh(wte[data] + wpe) -> bf16 [ROWS][DIM]
// One block per row, 192 threads * float4 = 768 elements
// ---------------------------------------------------------------------------
__global__ void build_x(const int* __restrict__ data, const float* __restrict__ wte,
                        const float* __restrict__ wpe, ushort* __restrict__ Xb) {
    const int row = blockIdx.x;
    const int s   = row & (SEQ - 1);
    const int tok = data[row];
    const int t   = threadIdx.x;   // 0..191
    float4 a = ((const float4*)(wte + (size_t)tok * DIM))[t];
    float4 p = ((const float4*)(wpe + (size_t)s   * DIM))[t];
    ushort4 o;
    o.x = f2b(gelu_tanh(a.x + p.x));
    o.y = f2b(gelu_tanh(a.y + p.y));
    o.z = f2b(gelu_tanh(a.z + p.z));
    o.w = f2b(gelu_tanh(a.w + p.w));
    ((ushort4*)Xb)[(size_t)row * (DIM / 4) + t] = o;
}

// ---------------------------------------------------------------------------
// Kernel 3: tiled bf16 MFMA "GEMM" producing per-(row, vocab-tile) softmax
// partials (max, sumexp) instead of materializing logits.
// 128x128 tile, BK=32, 4 waves (2x2), 4x4 16x16x32 fragments per wave.
// ---------------------------------------------------------------------------
__global__ __launch_bounds__(256) void gemm_partial(
    const ushort* __restrict__ Xb, const ushort* __restrict__ Wb,
    float2* __restrict__ parts)
{
    __shared__ ushort lA[128 * 32];
    __shared__ ushort lB[128 * 32];
    __shared__ float2 red[128][2];

    const int bid = blockIdx.x;
    // XCD-aware swizzle: nwg = 25152 = 8 * 3144 (bijective)
    const int swz = (bid & 7) * 3144 + (bid >> 3);
    const int bm = swz & 63;     // row tile (fast) -> 64 blocks share one W panel
    const int bn = swz >> 6;     // vocab tile 0..392
    const int tid = threadIdx.x;
    const int w = tid >> 6, l = tid & 63;
    const int wr = w >> 1, wc = w & 1;
    const int row0 = bm << 7, col0 = bn << 7;

    f32x4 acc[4][4] = {};

    // staging: wave w stages tile rows [w*32, w*32+32), two 16-row issues each
    const int srow = (w << 5) + (l >> 2);
    const int scol = (l & 3) << 3;            // element offset 0,8,16,24
    const ushort* gA = Xb + (size_t)(row0 + srow) * DIM + scol;
    const ushort* gB = Wb + (size_t)(col0 + srow) * DIM + scol;
    ushort* sA = &lA[(w << 5) * 32];
    ushort* sB = &lB[(w << 5) * 32];

    // fragment read pointers
    const int lrow = l & 15, lk = (l >> 4) << 3;
    const ushort* pa = &lA[(wr * 64 + lrow) * 32 + lk];
    const ushort* pb = &lB[(wc * 64 + lrow) * 32 + lk];

    for (int k0 = 0; k0 < DIM; k0 += 32) {
        async16(gA + k0,            sA);
        async16(gA + k0 + 16 * DIM, sA + 16 * 32);
        async16(gB + k0,            sB);
        async16(gB + k0 + 16 * DIM, sB + 16 * 32);
        __syncthreads();   // drains vmcnt -> LDS tiles complete

        bf16x8 af[4], bg[4];
        #pragma unroll
        for (int m = 0; m < 4; m++) af[m] = *(const bf16x8*)(pa + m * 16 * 32);
        #pragma unroll
        for (int n = 0; n < 4; n++) bg[n] = *(const bf16x8*)(pb + n * 16 * 32);

        #pragma unroll
        for (int m = 0; m < 4; m++)
            #pragma unroll
            for (int n = 0; n < 4; n++)
                acc[m][n] = __builtin_amdgcn_mfma_f32_16x16x32_bf16(
                    af[m], bg[n], acc[m][n], 0, 0, 0);
        __syncthreads();   // protect LDS before next-iter staging
    }

    // ------- epilogue: per-row masked max + sum(exp) over this 128-col tile
    const int qr = l >> 4, lc = l & 15;
    #pragma unroll
    for (int m = 0; m < 4; m++) {
        #pragma unroll
        for (int j = 0; j < 4; j++) {
            const int rloc = wr * 64 + m * 16 + qr * 4 + j;
            float vals[4];
            float vmax = -INFINITY;
            #pragma unroll
            for (int n = 0; n < 4; n++) {
                const int v = col0 + wc * 64 + n * 16 + lc;
                float x = acc[m][n][j];
                if (v >= VOCAB) x = -INFINITY;
                vals[n] = x;
                vmax = fmaxf(vmax, x);
            }
            #pragma unroll
            for (int off = 1; off < 16; off <<= 1)
                vmax = fmaxf(vmax, __shfl_xor(vmax, off, 64));
            float s = 0.f;
            #pragma unroll
            for (int n = 0; n < 4; n++)
                s += __expf(vals[n] - vmax);   // exp(-inf - m) = 0 for masked
            #pragma unroll
            for (int off = 1; off < 16; off <<= 1)
                s += __shfl_xor(s, off, 64);
            if (lc == 0) { red[rloc][wc].x = vmax; red[rloc][wc].y = s; }
        }
    }
    __syncthreads();
    if (tid < 128) {
        float2 a = red[tid][0], b = red[tid][1];
        float M = fmaxf(a.x, b.x);
        float S = a.y * __expf(a.x - M) + b.y * __expf(b.x - M);
        parts[(size_t)(row0 + tid) * NVB + bn] = make_float2(M, S);
    }
}

// ---------------------------------------------------------------------------
// Kernel 4: per-row merge of partials + label logit -> per-row loss
// One wave per row.
// ---------------------------------------------------------------------------
__global__ void finalize_k(const ushort* __restrict__ Xb, const ushort* __restrict__ Wb,
                           const int* __restrict__ label, const float2* __restrict__ parts,
                           float* __restrict__ losses) {
    const int r = blockIdx.x;
    const int l = threadIdx.x;  // 64
    const int tok = label[r];

    // label logit: dot(x[r], Wb[tok]) in f32 from bf16 operands (consistent w/ GEMM)
    float dot = 0.f;
    const ushort4* xr = (const ushort4*)(Xb + (size_t)r   * DIM);
    const ushort4* wv = (const ushort4*)(Wb + (size_t)tok * DIM);
    for (int q = l; q < DIM / 4; q += 64) {
        ushort4 a = xr[q], b = wv[q];
        dot += b2f(a.x) * b2f(b.x) + b2f(a.y) * b2f(b.y)
             + b2f(a.z) * b2f(b.z) + b2f(a.w) * b2f(b.w);
    }
    #pragma unroll
    for (int off = 1; off < 64; off <<= 1) dot += __shfl_xor(dot, off, 64);

    // merge NVB partials (online LSE)
    float M = -INFINITY, S = 0.f;
    for (int p = l; p < NVB; p += 64) {
        float2 e = parts[(size_t)r * NVB + p];
        float nm = fmaxf(M, e.x);
        S = S * __expf(M - nm) + e.y * __expf(e.x - nm);
        M = nm;
    }
    #pragma unroll
    for (int off = 1; off < 64; off <<= 1) {
        float Mo = __shfl_xor(M, off, 64);
        float So = __shfl_xor(S, off, 64);
        float nm = fmaxf(M, Mo);
        S = S * __expf(M - nm) + So * __expf(Mo - nm);
        M = nm;
    }
    if (l == 0) losses[r] = M + logf(S) - dot;
}

// ---------------------------------------------------------------------------
// Kernel 5: mean of per-row losses -> scalar
// ---------------------------------------------------------------------------
__global__ void reduce_loss(const float* __restrict__ losses, float* __restrict__ out) {
    __shared__ float sh[256];
    float s = 0.f;
    for (int i = threadIdx.x; i < ROWS; i += 256) s += losses[i];
    sh[threadIdx.x] = s;
    __syncthreads();
    for (int st = 128; st > 0; st >>= 1) {
        if (threadIdx.x < st) sh[threadIdx.x] += sh[threadIdx.x + st];
        __syncthreads();
    }
    if (threadIdx.x == 0) out[0] = sh[0] * (1.0f / (float)ROWS);
}

// ---------------------------------------------------------------------------
extern "C" void kernel_launch(void* const* d_in, const int* in_sizes, int n_in,
                              void* d_out, int out_size, void* d_ws, size_t ws_size,
                              hipStream_t stream) {
    const int*   data  = (const int*)d_in[0];
    const int*   label = (const int*)d_in[1];
    const float* wte   = (const float*)d_in[2];
    const float* wpe   = (const float*)d_in[3];
    const float* W     = (const float*)d_in[4];
    float*       out   = (float*)d_out;

    // workspace layout
    char* ws = (char*)d_ws;
    ushort* Wb    = (ushort*)ws;                                   // VPAD*DIM*2   = 77,266,944 B
    ushort* Xb    = (ushort*)(ws + (size_t)VPAD * DIM * 2);        // ROWS*DIM*2   = 12,582,912 B
    float2* parts = (float2*)(ws + (size_t)VPAD * DIM * 2
                                 + (size_t)ROWS * DIM * 2);        // ROWS*NVB*8   = 25,755,648 B
    float* losses = (float*)(ws + (size_t)VPAD * DIM * 2
                                + (size_t)ROWS * DIM * 2
                                + (size_t)ROWS * NVB * 8);         // ROWS*4 B

    convert_w<<<2048, 256, 0, stream>>>(W, Wb);
    build_x<<<ROWS, DIM / 4, 0, stream>>>(data, wte, wpe, Xb);
    gemm_partial<<<NMB * NVB, 256, 0, stream>>>(Xb, Wb, parts);
    finalize_k<<<ROWS, 64, 0, stream>>>(Xb, Wb, label, parts, losses);
    reduce_loss<<<1, 256, 0, stream>>>(losses, out);
}

// Round 5
// 1084.232 us; speedup vs baseline: 1.1329x; 1.1329x over previous
//
#include <hip/hip_runtime.h>
#include <hip/hip_bf16.h>
#include <cmath>

// Problem constants
#define BATCH   8
#define SEQ     1024
#define ROWS    8192        // BATCH*SEQ
#define DIM     768
#define VOCAB   50257
#define VPAD    50432       // VOCAB padded up to multiple of 256
#define NVB     197         // ceil(VOCAB/256) vocab tiles
#define NMB     32          // ROWS/256 row tiles
#define BK      32
#define NT      24          // DIM/BK
#define SLOT_B  32768       // bytes per LDS slot (A 16KB + B 16KB)

typedef __attribute__((ext_vector_type(8))) short bf16x8;
typedef __attribute__((ext_vector_type(4))) float f32x4;

__device__ __forceinline__ float b2f(ushort u) {
    return __uint_as_float(((unsigned int)u) << 16);
}

__device__ __forceinline__ ushort f2b(float f) {
    unsigned int u = __float_as_uint(f);
    u += 0x7FFFu + ((u >> 16) & 1u);   // round-to-nearest-even
    return (ushort)(u >> 16);
}

__device__ __forceinline__ float gelu_tanh(float x) {
    const float c = 0.7978845608028654f;   // sqrt(2/pi)
    float t = c * (x + 0.044715f * x * x * x);
    return 0.5f * x * (1.0f + tanhf(t));
}

__device__ __forceinline__ void async16(const void* g, void* l) {
    __builtin_amdgcn_global_load_lds((const __attribute__((address_space(1))) void*)g,
                                     (__attribute__((address_space(3))) void*)l,
                                     16, 0, 0);
}

// ---------------------------------------------------------------------------
// Kernel 1: W f32 -> bf16, zero-padded to VPAD rows
// ---------------------------------------------------------------------------
__global__ void convert_w(const float* __restrict__ W, ushort* __restrict__ Wb) {
    const size_t NQ  = (size_t)VPAD  * DIM / 4;
    const size_t NVQ = (size_t)VOCAB * DIM / 4;
    for (size_t q = (size_t)blockIdx.x * blockDim.x + threadIdx.x; q < NQ;
         q += (size_t)gridDim.x * blockDim.x) {
        ushort4 o;
        if (q < NVQ) {
            float4 f = ((const float4*)W)[q];
            o.x = f2b(f.x); o.y = f2b(f.y); o.z = f2b(f.z); o.w = f2b(f.w);
        } else {
            o.x = 0; o.y = 0; o.z = 0; o.w = 0;
        }
        ((ushort4*)Wb)[q] = o;
    }
}

// ---------------------------------------------------------------------------
// Kernel 2: x = gelu_tanh(wte[data] + wpe) -> bf16 [ROWS][DIM]
// ---------------------------------------------------------------------------
__global__ void build_x(const int* __restrict__ data, const float* __restrict__ wte,
                        const float* __restrict__ wpe, ushort* __restrict__ Xb) {
    const int row = blockIdx.x;
    const int s   = row & (SEQ - 1);
    const int tok = data[row];
    const int t   = threadIdx.x;   // 0..191
    float4 a = ((const float4*)(wte + (size_t)tok * DIM))[t];
    float4 p = ((const float4*)(wpe + (size_t)s   * DIM))[t];
    ushort4 o;
    o.x = f2b(gelu_tanh(a.x + p.x));
    o.y = f2b(gelu_tanh(a.y + p.y));
    o.z = f2b(gelu_tanh(a.z + p.z));
    o.w = f2b(gelu_tanh(a.w + p.w));
    ((ushort4*)Xb)[(size_t)row * (DIM / 4) + t] = o;
}

// ---------------------------------------------------------------------------
// Kernel 3: 256x256 tile, BK=32, 8 waves (2Mx4N), 4-slot LDS (128 KiB),
// depth-3 prefetch with counted vmcnt(8), T2 XOR-swizzle, setprio on MFMA.
// Produces per-(row, vocab-tile-256) softmax partials (max, sumexp).
// ---------------------------------------------------------------------------
__global__ __launch_bounds__(512, 2) void gemm_partial(
    const ushort* __restrict__ Xb, const ushort* __restrict__ Wb,
    float2* __restrict__ parts)
{
    __shared__ ushort tiles[4 * SLOT_B / 2];   // 128 KiB: 4 slots x (A 16K | B 16K)
    char* smemc = (char*)tiles;

    const int bid = blockIdx.x;
    // XCD-partitioned mapping: xcd owns bm range [xcd*4, xcd*4+4) x all 197 bn.
    // 6304 = 8 * 788, 788 = 4 * 197 -> exact bijection.
    const int xcd = bid & 7, idx = bid >> 3;
    const int bm = xcd * 4 + (idx & 3);
    const int bn = idx >> 2;
    const int row0 = bm << 8, col0 = bn << 8;

    const int tid = threadIdx.x;
    const int w = tid >> 6, l = tid & 63;
    const int wr = w >> 2, wc = w & 3;         // wave grid 2(M) x 4(N)

    // ---- staging addresses (inverse-swizzled global source, linear LDS dest)
    // LDS linear byte (within 8K chunk) = w*1024 + l*16 -> row = w*16 + (l>>2),
    // physical chunk c' = l&3.  Logical chunk = c' ^ ((row>>1)&3) = (l&3)^((l>>3)&3).
    const int rstage = w * 16 + (l >> 2);                 // 0..127
    const int cswz   = ((l & 3) ^ ((l >> 3) & 3)) << 3;   // element offset
    const ushort* gA0 = Xb + (size_t)(row0 + rstage) * DIM + cswz;
    const ushort* gA1 = gA0 + (size_t)128 * DIM;
    const ushort* gB0 = Wb + (size_t)(col0 + rstage) * DIM + cswz;
    const ushort* gB1 = gB0 + (size_t)128 * DIM;
    char* ldsA = smemc + w * 1024;            // + slot*SLOT_B (+8192 for half 1)
    char* ldsB = smemc + 16384 + w * 1024;

    // ---- swizzled fragment-read byte offsets
    const int lrow = l & 15, cexp = l >> 4;
    const int swzs = (lrow >> 1) & 3;
    const int aoff = (wr * 128 + lrow) * 64 + ((cexp ^ swzs) << 4);          // + m*1024
    const int boff = 16384 + (wc * 64 + lrow) * 64 + ((cexp ^ swzs) << 4);   // + n*1024

    f32x4 acc[8][4] = {};

#define GL(t, s) do {                                         \
        const int koff_ = (t) * BK;                           \
        async16(gA0 + koff_, ldsA + (s) * SLOT_B);            \
        async16(gA1 + koff_, ldsA + (s) * SLOT_B + 8192);     \
        async16(gB0 + koff_, ldsB + (s) * SLOT_B);            \
        async16(gB1 + koff_, ldsB + (s) * SLOT_B + 8192);     \
    } while (0)

#define COMPUTE(t) do {                                                       \
        const char* sb_ = smemc + ((t) & 3) * SLOT_B;                         \
        bf16x8 af_[8], bg_[4];                                                \
        _Pragma("unroll")                                                     \
        for (int m_ = 0; m_ < 8; m_++)                                        \
            af_[m_] = *(const bf16x8*)(sb_ + aoff + m_ * 1024);               \
        _Pragma("unroll")                                                     \
        for (int n_ = 0; n_ < 4; n_++)                                        \
            bg_[n_] = *(const bf16x8*)(sb_ + boff + n_ * 1024);               \
        __builtin_amdgcn_s_setprio(1);                                        \
        _Pragma("unroll")                                                     \
        for (int m_ = 0; m_ < 8; m_++)                                        \
            _Pragma("unroll")                                                 \
            for (int n_ = 0; n_ < 4; n_++)                                    \
                acc[m_][n_] = __builtin_amdgcn_mfma_f32_16x16x32_bf16(        \
                    af_[m_], bg_[n_], acc[m_][n_], 0, 0, 0);                  \
        __builtin_amdgcn_s_setprio(0);                                        \
    } while (0)

    // prologue: stage tiles 0,1,2 into slots 0,1,2 (12 loads/wave in flight)
    GL(0, 0); GL(1, 1); GL(2, 2);
    asm volatile("s_waitcnt vmcnt(8)" ::: "memory");   // tile 0 (my slice) landed
    __builtin_amdgcn_s_barrier();                      // -> collectively landed
    asm volatile("" ::: "memory");

    // steady state: compute t, stage t+3, wait until tile t+1 landed
    for (int t = 0; t < NT - 3; ++t) {                 // t = 0..20
        GL(t + 3, (t + 3) & 3);
        COMPUTE(t);
        asm volatile("s_waitcnt vmcnt(8)" ::: "memory");
        __builtin_amdgcn_s_barrier();
        asm volatile("" ::: "memory");
    }
    COMPUTE(21);
    asm volatile("s_waitcnt vmcnt(4)" ::: "memory");
    __builtin_amdgcn_s_barrier();
    asm volatile("" ::: "memory");
    COMPUTE(22);
    asm volatile("s_waitcnt vmcnt(0)" ::: "memory");
    __builtin_amdgcn_s_barrier();
    asm volatile("" ::: "memory");
    COMPUTE(23);

#undef GL
#undef COMPUTE

    // ------- epilogue: per-row masked max + sum(exp) over this 256-col tile
    __syncthreads();                                   // slots dead; alias red
    float2 (*red)[4] = (float2(*)[4])smemc;            // [256][4], 8 KiB

    const int qr = l >> 4, lc = l & 15;
    #pragma unroll
    for (int m = 0; m < 8; m++) {
        #pragma unroll
        for (int j = 0; j < 4; j++) {
            const int rloc = wr * 128 + m * 16 + qr * 4 + j;
            float vals[4];
            float vmax = -INFINITY;
            #pragma unroll
            for (int n = 0; n < 4; n++) {
                const int v = col0 + wc * 64 + n * 16 + lc;
                float x = acc[m][n][j];
                if (v >= VOCAB) x = -INFINITY;
                vals[n] = x;
                vmax = fmaxf(vmax, x);
            }
            #pragma unroll
            for (int off = 1; off < 16; off <<= 1)
                vmax = fmaxf(vmax, __shfl_xor(vmax, off, 64));
            float s = 0.f;
            #pragma unroll
            for (int n = 0; n < 4; n++)
                s += (vals[n] == -INFINITY) ? 0.f : __expf(vals[n] - vmax);
            #pragma unroll
            for (int off = 1; off < 16; off <<= 1)
                s += __shfl_xor(s, off, 64);
            if (lc == 0) { red[rloc][wc].x = vmax; red[rloc][wc].y = s; }
        }
    }
    __syncthreads();
    if (tid < 256) {
        float M = -INFINITY, S = 0.f;
        #pragma unroll
        for (int q = 0; q < 4; q++) {
            float2 e = red[tid][q];
            float nm = fmaxf(M, e.x);
            S = S * __expf(M - nm) + e.y * __expf(e.x - nm);
            M = nm;
        }
        parts[(size_t)(row0 + tid) * NVB + bn] = make_float2(M, S);
    }
}

// ---------------------------------------------------------------------------
// Kernel 4: per-row merge of partials + label logit -> per-row loss
// ---------------------------------------------------------------------------
__global__ void finalize_k(const ushort* __restrict__ Xb, const ushort* __restrict__ Wb,
                           const int* __restrict__ label, const float2* __restrict__ parts,
                           float* __restrict__ losses) {
    const int r = blockIdx.x;
    const int l = threadIdx.x;  // 64
    const int tok = label[r];

    float dot = 0.f;
    const ushort4* xr = (const ushort4*)(Xb + (size_t)r   * DIM);
    const ushort4* wv = (const ushort4*)(Wb + (size_t)tok * DIM);
    for (int q = l; q < DIM / 4; q += 64) {
        ushort4 a = xr[q], b = wv[q];
        dot += b2f(a.x) * b2f(b.x) + b2f(a.y) * b2f(b.y)
             + b2f(a.z) * b2f(b.z) + b2f(a.w) * b2f(b.w);
    }
    #pragma unroll
    for (int off = 1; off < 64; off <<= 1) dot += __shfl_xor(dot, off, 64);

    float M = -INFINITY, S = 0.f;
    for (int p = l; p < NVB; p += 64) {
        float2 e = parts[(size_t)r * NVB + p];
        float nm = fmaxf(M, e.x);
        S = S * __expf(M - nm) + e.y * __expf(e.x - nm);
        M = nm;
    }
    #pragma unroll
    for (int off = 1; off < 64; off <<= 1) {
        float Mo = __shfl_xor(M, off, 64);
        float So = __shfl_xor(S, off, 64);
        float nm = fmaxf(M, Mo);
        S = S * __expf(M - nm) + So * __expf(Mo - nm);
        M = nm;
    }
    if (l == 0) losses[r] = M + logf(S) - dot;
}

// ---------------------------------------------------------------------------
// Kernel 5: mean of per-row losses -> scalar
// ---------------------------------------------------------------------------
__global__ void reduce_loss(const float* __restrict__ losses, float* __restrict__ out) {
    __shared__ float sh[256];
    float s = 0.f;
    for (int i = threadIdx.x; i < ROWS; i += 256) s += losses[i];
    sh[threadIdx.x] = s;
    __syncthreads();
    for (int st = 128; st > 0; st >>= 1) {
        if (threadIdx.x < st) sh[threadIdx.x] += sh[threadIdx.x + st];
        __syncthreads();
    }
    if (threadIdx.x == 0) out[0] = sh[0] * (1.0f / (float)ROWS);
}

// ---------------------------------------------------------------------------
extern "C" void kernel_launch(void* const* d_in, const int* in_sizes, int n_in,
                              void* d_out, int out_size, void* d_ws, size_t ws_size,
                              hipStream_t stream) {
    const int*   data  = (const int*)d_in[0];
    const int*   label = (const int*)d_in[1];
    const float* wte   = (const float*)d_in[2];
    const float* wpe   = (const float*)d_in[3];
    const float* W     = (const float*)d_in[4];
    float*       out   = (float*)d_out;

    // workspace layout
    char* ws = (char*)d_ws;
    ushort* Wb    = (ushort*)ws;                                   // VPAD*DIM*2 = 77,463,552 B
    ushort* Xb    = (ushort*)(ws + (size_t)VPAD * DIM * 2);        // ROWS*DIM*2 = 12,582,912 B
    float2* parts = (float2*)(ws + (size_t)VPAD * DIM * 2
                                 + (size_t)ROWS * DIM * 2);        // ROWS*NVB*8 = 12,910,592 B
    float* losses = (float*)(ws + (size_t)VPAD * DIM * 2
                                + (size_t)ROWS * DIM * 2
                                + (size_t)ROWS * NVB * 8);         // ROWS*4 B

    convert_w<<<2048, 256, 0, stream>>>(W, Wb);
    build_x<<<ROWS, DIM / 4, 0, stream>>>(data, wte, wpe, Xb);
    gemm_partial<<<NMB * NVB, 512, 0, stream>>>(Xb, Wb, parts);
    finalize_k<<<ROWS, 64, 0, stream>>>(Xb, Wb, label, parts, losses);
    reduce_loss<<<1, 256, 0, stream>>>(losses, out);
}